// Round 10
// baseline (1704.597 us; speedup 1.0000x reference)
//
#include <hip/hip_runtime.h>

#define NPIX 9216
#define IMH 96
#define IMW 96
#define NC 21
#define NCH 22          // 21 classes + norm channel
#define CP 24           // pixel-major channel pad
#define NMON 126        // monomials of degree <=4 in 5 vars
#define RAD 15
#define NITER 5
#define MG 11           // monomials per stage1 tile
#define NMG 12          // ceil(126/11)
#define LDSS 260        // stage1 LDS pitch
#define MPAD 2816       // M buffer stride
#define NBLK 512        // persistent grid: 2 blocks/CU, co-residency proven

// spatial taps exp(-d^2/18), sigma=3
__constant__ float GW[16] = {
    1.0f, 0.945959f, 0.800737f, 0.606531f, 0.411112f, 0.249352f,
    0.135335f, 0.0657285f, 0.0285655f, 0.0111090f, 0.00386592f,
    0.00120386f, 0.000335463f, 8.36523e-05f, 1.86640e-05f, 3.72665e-06f};

// near-minimax deg-4 poly for exp(t) on [0, 1.0384] (all coeffs > 0)
__constant__ float d_bk[5] = {1.000000f, 0.998959f, 0.509936f, 0.139441f, 0.070024f};

__device__ __forceinline__ void gbar(unsigned* bar, int idx) {
    __syncthreads();
    __threadfence();   // release: agent-scope writeback of dirty L1/L2
    if (threadIdx.x == 0) {
        __hip_atomic_fetch_add(&bar[idx], 1u, __ATOMIC_ACQ_REL,
                               __HIP_MEMORY_SCOPE_AGENT);
        while (__hip_atomic_load(&bar[idx], __ATOMIC_ACQUIRE,
                                 __HIP_MEMORY_SCOPE_AGENT) < (unsigned)NBLK)
            __builtin_amdgcn_s_sleep(8);
    }
    __syncthreads();
    __threadfence();   // acquire: invalidate L1/L2 so plain loads see remote writes
}

__global__ __launch_bounds__(256, 2) void mega_kernel(
    const float* __restrict__ img, const float* __restrict__ net_w,
    const float* __restrict__ net_b,
    const float* __restrict__ sp_w, const float* __restrict__ sp_b,
    const float* __restrict__ bl_w, const float* __restrict__ bl_b,
    const float* __restrict__ comp_w, const float* __restrict__ comp_b,
    unsigned* bar, float* M,
    float* u_pm, float* s_pm, float* s_cm, float* sx, float* phi,
    float* out)
{
    __shared__ float smem[11648];   // 46.6 KB, aliased per phase
    const int bid = blockIdx.x, tid = threadIdx.x;

    // ================= phase P: prep (blocks 0..35) =================
    if (bid < 36) {
        float* wsh = smem;            // 588
        float* sg_sh = smem + 588;    // 126
        float* ex_sh = smem + 714;    // 630
        float* pt = smem + 1344;      // 256*25
        for (int i = tid; i < 567; i += 256) wsh[i] = net_w[i];
        if (tid < 21) wsh[567 + tid] = net_b[tid];
        for (int m = tid; m < NMON; m += 256) {
            int e1 = 0, e2 = 0, e3 = 0, e4 = 0, e5 = 0, cnt = 0;
            bool done = false;
            for (int a = 0; a <= 4 && !done; a++)
                for (int b2 = 0; b2 <= 4 - a && !done; b2++)
                    for (int c = 0; c <= 4 - a - b2 && !done; c++)
                        for (int d = 0; d <= 4 - a - b2 - c && !done; d++) {
                            const int rem = 4 - a - b2 - c - d;
                            if (m - cnt <= rem) {
                                e1 = a; e2 = b2; e3 = c; e4 = d; e5 = m - cnt;
                                done = true;
                            } else cnt += rem + 1;
                        }
            const float fact[5] = {1.f, 1.f, 2.f, 6.f, 24.f};
            const int k = e1 + e2 + e3 + e4 + e5;
            sg_sh[m] = sqrtf(d_bk[k] * fact[k] /
                             (fact[e1] * fact[e2] * fact[e3] * fact[e4] * fact[e5]));
            ex_sh[m * 5 + 0] = (float)e1; ex_sh[m * 5 + 1] = (float)e2;
            ex_sh[m * 5 + 2] = (float)e3; ex_sh[m * 5 + 3] = (float)e4;
            ex_sh[m * 5 + 4] = (float)e5;
        }
        __syncthreads();

        const int px = bid * 256 + tid;
        const int i = px / IMW, j = px % IMW;
        float acc[NC];
        #pragma unroll
        for (int o = 0; o < NC; o++) acc[o] = wsh[567 + o];
        for (int ci = 0; ci < 3; ci++)
            for (int ky = 0; ky < 3; ky++)
                for (int kx = 0; kx < 3; kx++) {
                    const int ii = i + ky - 1, jj = j + kx - 1;
                    float v = 0.f;
                    if (ii >= 0 && ii < IMH && jj >= 0 && jj < IMW)
                        v = img[(ci * IMH + ii) * IMW + jj];
                    #pragma unroll
                    for (int o = 0; o < NC; o++)
                        acc[o] = fmaf(v, wsh[(ci * 3 + ky) * 3 + kx + o * 27], acc[o]);
                }
        {
            float4* up = (float4*)(u_pm + (size_t)px * CP);
            up[0] = make_float4(acc[0], acc[1], acc[2], acc[3]);
            up[1] = make_float4(acc[4], acc[5], acc[6], acc[7]);
            up[2] = make_float4(acc[8], acc[9], acc[10], acc[11]);
            up[3] = make_float4(acc[12], acc[13], acc[14], acc[15]);
            up[4] = make_float4(acc[16], acc[17], acc[18], acc[19]);
            up[5] = make_float4(acc[20], 0.f, 0.f, 0.f);
        }
        float mx = acc[0];
        #pragma unroll
        for (int o = 1; o < NC; o++) mx = fmaxf(mx, acc[o]);
        float sum = 0.f;
        #pragma unroll
        for (int o = 0; o < NC; o++) { acc[o] = __expf(acc[o] - mx); sum += acc[o]; }
        const float inv = 1.f / sum;
        #pragma unroll
        for (int o = 0; o < NC; o++) acc[o] *= inv;
        {
            float4* sp = (float4*)(s_pm + (size_t)px * CP);
            sp[0] = make_float4(acc[0], acc[1], acc[2], acc[3]);
            sp[1] = make_float4(acc[4], acc[5], acc[6], acc[7]);
            sp[2] = make_float4(acc[8], acc[9], acc[10], acc[11]);
            sp[3] = make_float4(acc[12], acc[13], acc[14], acc[15]);
            sp[4] = make_float4(acc[16], acc[17], acc[18], acc[19]);
            sp[5] = make_float4(acc[20], 1.f, 0.f, 0.f);
        }
        #pragma unroll
        for (int o = 0; o < NC; o++) s_cm[(size_t)o * NPIX + px] = acc[o];
        s_cm[(size_t)21 * NPIX + px] = 1.f;

        const float fv[5] = {(float)j * (1.0f / 160.0f), (float)i * (1.0f / 160.0f),
                             img[0 * NPIX + px] * (1.0f / 3.0f),
                             img[1 * NPIX + px] * (1.0f / 3.0f),
                             img[2 * NPIX + px] * (1.0f / 3.0f)};
        const float env = __expf(-0.5f * (fv[0]*fv[0] + fv[1]*fv[1] + fv[2]*fv[2] +
                                          fv[3]*fv[3] + fv[4]*fv[4]));
        #pragma unroll
        for (int v = 0; v < 5; v++) {
            float p = 1.f;
            #pragma unroll
            for (int e = 0; e < 5; e++) { pt[tid * 25 + v * 5 + e] = p; p *= fv[v]; }
        }
        for (int m = 0; m < NMON; m++) {
            float p = env * sg_sh[m];
            p *= pt[tid * 25 + 0 + (int)ex_sh[m * 5 + 0]];
            p *= pt[tid * 25 + 5 + (int)ex_sh[m * 5 + 1]];
            p *= pt[tid * 25 + 10 + (int)ex_sh[m * 5 + 2]];
            p *= pt[tid * 25 + 15 + (int)ex_sh[m * 5 + 3]];
            p *= pt[tid * 25 + 20 + (int)ex_sh[m * 5 + 4]];
            phi[(size_t)m * NPIX + px] = p;
        }
    }
    gbar(bar, 0);

    // ================= iterations =================
    for (int it = 0; it < NITER; it++) {
        float* Mc = M + (it & 1) * MPAD;
        float* Mn = M + ((it + 1) & 1) * MPAD;

        // ---- phase A: stage1 tiles (432 block-tasks) + conv-x (792) ----
        for (int bt = bid; bt < NMG * 36 + NCH * 36; bt += NBLK) {
            if (bt < NMG * 36) {
                const int g = bt / 36, chunk = bt % 36;
                const int m0 = g * MG;
                const int mcnt = (NMON - m0 < MG) ? (NMON - m0) : MG;
                float* s_sh = smem;
                float* p_sh = smem + NCH * LDSS;
                __syncthreads();
                {
                    const float4* sp =
                        (const float4*)(s_pm + (size_t)(chunk * 256 + tid) * CP);
                    #pragma unroll
                    for (int v = 0; v < 6; v++) {
                        const float4 t = sp[v];
                        const int c = 4 * v;
                        if (c < NCH)     s_sh[c * LDSS + tid] = t.x;
                        if (c + 1 < NCH) s_sh[(c + 1) * LDSS + tid] = t.y;
                        if (c + 2 < NCH) s_sh[(c + 2) * LDSS + tid] = t.z;
                        if (c + 3 < NCH) s_sh[(c + 3) * LDSS + tid] = t.w;
                    }
                }
                for (int idx = tid; idx < mcnt * 64; idx += 256) {
                    const int mm = idx >> 6, p4 = idx & 63;
                    const float4 t = *(const float4*)(phi + (size_t)(m0 + mm) * NPIX +
                                                      chunk * 256 + p4 * 4);
                    *(float4*)(p_sh + mm * LDSS + p4 * 4) = t;
                }
                __syncthreads();
                const int c = tid % NCH, msub = tid / NCH;
                if (msub < mcnt) {
                    const float* sr = s_sh + c * LDSS;
                    const float* pr = p_sh + msub * LDSS;
                    float acc = 0.f;
                    for (int p4 = 0; p4 < 64; p4++) {
                        const float4 sv = *(const float4*)(sr + p4 * 4);
                        const float4 pv = *(const float4*)(pr + p4 * 4);
                        acc += pv.x * sv.x + pv.y * sv.y + pv.z * sv.z + pv.w * sv.w;
                    }
                    atomicAdd(&Mc[(m0 + msub) * NCH + c], acc);
                }
            } else {
                const int u2 = bt - NMG * 36;
                const int ch = u2 / 36, pc = u2 % 36;
                const int n = pc * 256 + tid, j = n % IMW;
                const float* row = s_cm + (size_t)ch * NPIX + (n - j);
                float a = GW[0] * row[j];
                #pragma unroll
                for (int d = 1; d <= RAD; d++) {
                    const float l = (j - d >= 0) ? row[j - d] : 0.f;
                    const float r = (j + d < IMW) ? row[j + d] : 0.f;
                    a = fmaf(GW[d], l + r, a);
                }
                sx[(size_t)ch * NPIX + n] = a;
            }
        }
        gbar(bar, 1 + 2 * it);

        // ---- phase B: conv-y + stage2 + combine + softmax (288 tasks) ----
        if (bid < 288) {
            float* Msh = smem;             // 3024
            float* phi_sh = smem + 3024;   // 4032
            float* cy_sh = smem + 7056;    // 800
            float* blv_sh = smem + 7856;   // 800
            float* mp_sh = smem + 8656;    // 768
            float* q_sh = smem + 9424;     // 768
            float* wsh = smem + 10192;     // 1449
            const int px0 = bid * 32;
            const int i0 = px0 / IMW;

            __syncthreads();
            for (int idx = tid; idx < NMON * CP; idx += 256) {
                const int mm = idx / CP, c = idx % CP;
                Msh[idx] = (c < NCH) ? Mc[mm * NCH + c] : 0.f;
            }
            for (int idx = tid; idx < 441; idx += 256) {
                wsh[idx] = sp_w[idx]; wsh[441 + idx] = bl_w[idx];
                wsh[882 + idx] = comp_w[idx];
            }
            if (tid < 21) {
                wsh[1323 + tid] = sp_b[tid]; wsh[1344 + tid] = bl_b[tid];
                wsh[1365 + tid] = comp_b[tid];
            }
            if (bid < 11) {
                const int idx = bid * 256 + tid;
                if (idx < 2772) Mn[idx] = 0.f;
            }
            for (int idx = tid; idx < NMON * 8; idx += 256) {
                const int m = idx >> 3, g = idx & 7;
                *(float4*)(phi_sh + m * 32 + g * 4) =
                    *(const float4*)(phi + (size_t)m * NPIX + px0 + g * 4);
            }
            for (int task = tid; task < 24 * 32; task += 256) {
                const int ch = task >> 5, p = task & 31;
                if (ch < NCH) {
                    const int n = px0 + p;
                    const float* plane = sx + (size_t)ch * NPIX;
                    float a = GW[0] * plane[n];
                    #pragma unroll
                    for (int d = 1; d <= RAD; d++) {
                        const float t = (i0 - d >= 0) ? plane[n - d * IMW] : 0.f;
                        const float b = (i0 + d < IMH) ? plane[n + d * IMW] : 0.f;
                        a = fmaf(GW[d], t + b, a);
                    }
                    cy_sh[p * 25 + ch] = a;
                }
            }
            __syncthreads();
            {
                const int p = tid & 31, c0 = (tid >> 5) * 3;
                float a0 = 0.f, a1 = 0.f, a2 = 0.f;
                for (int mm = 0; mm < NMON; mm++) {
                    const float ph = phi_sh[mm * 32 + p];
                    const float* Mr = Msh + mm * CP + c0;
                    a0 = fmaf(ph, Mr[0], a0);
                    a1 = fmaf(ph, Mr[1], a1);
                    a2 = fmaf(ph, Mr[2], a2);
                }
                if (c0 < NCH)     blv_sh[p * 25 + c0] = a0;
                if (c0 + 1 < NCH) blv_sh[p * 25 + c0 + 1] = a1;
                if (c0 + 2 < NCH) blv_sh[p * 25 + c0 + 2] = a2;
            }
            __syncthreads();
            for (int t = tid; t < 672; t += 256) {
                const int p = t & 31, o = t >> 5;
                const float* cyr = cy_sh + p * 25;
                const float* blr = blv_sh + p * 25;
                float dS = 0.f, dB = 0.f;
                #pragma unroll
                for (int c = 0; c < NC; c++) {
                    dS = fmaf(wsh[o * NC + c], cyr[c], dS);
                    dB = fmaf(wsh[441 + o * NC + c], blr[c], dB);
                }
                mp_sh[p * CP + o] = wsh[1323 + o] + wsh[1344 + o] +
                                    dS / cyr[21] + dB / blr[21];
            }
            __syncthreads();
            for (int t = tid; t < 672; t += 256) {
                const int p = t & 31, o = t >> 5;
                const float* mpr = mp_sh + p * CP;
                float d = wsh[1365 + o];
                #pragma unroll
                for (int c = 0; c < NC; c++)
                    d = fmaf(wsh[882 + o * NC + c], mpr[c], d);
                q_sh[p * CP + o] = u_pm[(size_t)(px0 + p) * CP + o] - d;
            }
            __syncthreads();
            if (tid < 32) {
                const int n = px0 + tid;
                float q[NC];
                #pragma unroll
                for (int o = 0; o < NC; o++) q[o] = q_sh[tid * CP + o];
                float mx = q[0];
                #pragma unroll
                for (int o = 1; o < NC; o++) mx = fmaxf(mx, q[o]);
                float sum = 0.f;
                #pragma unroll
                for (int o = 0; o < NC; o++) { q[o] = __expf(q[o] - mx); sum += q[o]; }
                const float inv = 1.f / sum;
                #pragma unroll
                for (int o = 0; o < NC; o++) q[o] *= inv;

                float4* sp = (float4*)(s_pm + (size_t)n * CP);
                sp[0] = make_float4(q[0], q[1], q[2], q[3]);
                sp[1] = make_float4(q[4], q[5], q[6], q[7]);
                sp[2] = make_float4(q[8], q[9], q[10], q[11]);
                sp[3] = make_float4(q[12], q[13], q[14], q[15]);
                sp[4] = make_float4(q[16], q[17], q[18], q[19]);
                sp[5] = make_float4(q[20], 1.f, 0.f, 0.f);
                #pragma unroll
                for (int o = 0; o < NC; o++) s_cm[(size_t)o * NPIX + n] = q[o];
                s_cm[(size_t)21 * NPIX + n] = 1.f;
                if (it == NITER - 1)
                    #pragma unroll
                    for (int o = 0; o < NC; o++) out[(size_t)o * NPIX + n] = q[o];
            }
        }
        if (it < NITER - 1) gbar(bar, 2 + 2 * it);
    }
}

extern "C" void kernel_launch(void* const* d_in, const int* in_sizes, int n_in,
                              void* d_out, int out_size, void* d_ws, size_t ws_size,
                              hipStream_t stream) {
    const float* img    = (const float*)d_in[0];
    const float* net_w  = (const float*)d_in[1];
    const float* net_b  = (const float*)d_in[2];
    const float* sp_w   = (const float*)d_in[3];
    const float* sp_b   = (const float*)d_in[4];
    const float* bl_w   = (const float*)d_in[5];
    const float* bl_b   = (const float*)d_in[6];
    const float* comp_w = (const float*)d_in[7];
    const float* comp_b = (const float*)d_in[8];

    unsigned* bar = (unsigned*)d_ws;             // 16 slots
    float* M    = (float*)d_ws + 16;             // [2][MPAD]
    float* u_pm = M + 2 * MPAD;                  // [NPIX][24]
    float* s_pm = u_pm + (size_t)NPIX * CP;      // [NPIX][24]
    float* s_cm = s_pm + (size_t)NPIX * CP;      // [22][NPIX]
    float* sx   = s_cm + (size_t)NCH * NPIX;     // [22][NPIX]
    float* phi  = sx + (size_t)NCH * NPIX;       // [126][NPIX]

    hipMemsetAsync(d_ws, 0, (16 + 2 * MPAD) * sizeof(float), stream);
    mega_kernel<<<dim3(NBLK), dim3(256), 0, stream>>>(
        img, net_w, net_b, sp_w, sp_b, bl_w, bl_b, comp_w, comp_b,
        bar, M, u_pm, s_pm, s_cm, sx, phi, (float*)d_out);
}

// Round 11
// 832.216 us; speedup vs baseline: 2.0483x; 2.0483x over previous
//
#include <hip/hip_runtime.h>

#define NPIX 9216
#define IMH 96
#define IMW 96
#define NC 21
#define NCH 22          // 21 classes + norm channel
#define CP 24           // pixel-major channel pad
#define NMON 126        // monomials of degree <=4 in 5 vars
#define RAD 15
#define NITER 5
#define MG 11           // monomials per stage1 tile
#define NMG 12          // ceil(126/11)
#define LDSS 260        // stage1 LDS pitch
#define MPAD 2816       // M buffer stride
#define NBLK 288        // persistent grid: <=2 blocks/CU, co-residency proven

// spatial taps exp(-d^2/18), sigma=3
__constant__ float GW[16] = {
    1.0f, 0.945959f, 0.800737f, 0.606531f, 0.411112f, 0.249352f,
    0.135335f, 0.0657285f, 0.0285655f, 0.0111090f, 0.00386592f,
    0.00120386f, 0.000335463f, 8.36523e-05f, 1.86640e-05f, 3.72665e-06f};

// near-minimax deg-4 poly for exp(t) on [0, 1.0384] (all coeffs > 0)
__constant__ float d_bk[5] = {1.000000f, 0.998959f, 0.509936f, 0.139441f, 0.070024f};

// Grid barrier. RELAXED spin (no per-poll cache invalidate!) + one release
// fence before arrival and one acquire fence after the spin. s_sleep(32)
// (~0.85us) keeps poll traffic negligible.
__device__ __forceinline__ void gbar(unsigned* bar, int idx) {
    __syncthreads();
    __threadfence();   // release: flush dirty lines toward coherence point
    if (threadIdx.x == 0) {
        __hip_atomic_fetch_add(&bar[idx], 1u, __ATOMIC_RELAXED,
                               __HIP_MEMORY_SCOPE_AGENT);
        while (__hip_atomic_load(&bar[idx], __ATOMIC_RELAXED,
                                 __HIP_MEMORY_SCOPE_AGENT) < (unsigned)NBLK)
            __builtin_amdgcn_s_sleep(32);
    }
    __syncthreads();
    __threadfence();   // acquire: invalidate stale lines ONCE, then plain loads
}

__global__ __launch_bounds__(256, 2) void mega_kernel(
    const float* __restrict__ img, const float* __restrict__ net_w,
    const float* __restrict__ net_b,
    const float* __restrict__ sp_w, const float* __restrict__ sp_b,
    const float* __restrict__ bl_w, const float* __restrict__ bl_b,
    const float* __restrict__ comp_w, const float* __restrict__ comp_b,
    unsigned* bar, float* M,
    float* u_pm, float* s_pm, float* s_cm, float* sx, float* phi,
    float* out)
{
    __shared__ float smem[11648];   // 46.6 KB, aliased per phase
    const int bid = blockIdx.x, tid = threadIdx.x;

    // ================= phase P: prep (blocks 0..35) =================
    if (bid < 36) {
        float* wsh = smem;            // 588
        float* sg_sh = smem + 588;    // 126
        float* ex_sh = smem + 714;    // 630
        float* pt = smem + 1344;      // 256*25
        for (int i = tid; i < 567; i += 256) wsh[i] = net_w[i];
        if (tid < 21) wsh[567 + tid] = net_b[tid];
        for (int m = tid; m < NMON; m += 256) {
            int e1 = 0, e2 = 0, e3 = 0, e4 = 0, e5 = 0, cnt = 0;
            bool done = false;
            for (int a = 0; a <= 4 && !done; a++)
                for (int b2 = 0; b2 <= 4 - a && !done; b2++)
                    for (int c = 0; c <= 4 - a - b2 && !done; c++)
                        for (int d = 0; d <= 4 - a - b2 - c && !done; d++) {
                            const int rem = 4 - a - b2 - c - d;
                            if (m - cnt <= rem) {
                                e1 = a; e2 = b2; e3 = c; e4 = d; e5 = m - cnt;
                                done = true;
                            } else cnt += rem + 1;
                        }
            const float fact[5] = {1.f, 1.f, 2.f, 6.f, 24.f};
            const int k = e1 + e2 + e3 + e4 + e5;
            sg_sh[m] = sqrtf(d_bk[k] * fact[k] /
                             (fact[e1] * fact[e2] * fact[e3] * fact[e4] * fact[e5]));
            ex_sh[m * 5 + 0] = (float)e1; ex_sh[m * 5 + 1] = (float)e2;
            ex_sh[m * 5 + 2] = (float)e3; ex_sh[m * 5 + 3] = (float)e4;
            ex_sh[m * 5 + 4] = (float)e5;
        }
        __syncthreads();

        const int px = bid * 256 + tid;
        const int i = px / IMW, j = px % IMW;
        float acc[NC];
        #pragma unroll
        for (int o = 0; o < NC; o++) acc[o] = wsh[567 + o];
        for (int ci = 0; ci < 3; ci++)
            for (int ky = 0; ky < 3; ky++)
                for (int kx = 0; kx < 3; kx++) {
                    const int ii = i + ky - 1, jj = j + kx - 1;
                    float v = 0.f;
                    if (ii >= 0 && ii < IMH && jj >= 0 && jj < IMW)
                        v = img[(ci * IMH + ii) * IMW + jj];
                    #pragma unroll
                    for (int o = 0; o < NC; o++)
                        acc[o] = fmaf(v, wsh[(ci * 3 + ky) * 3 + kx + o * 27], acc[o]);
                }
        {
            float4* up = (float4*)(u_pm + (size_t)px * CP);
            up[0] = make_float4(acc[0], acc[1], acc[2], acc[3]);
            up[1] = make_float4(acc[4], acc[5], acc[6], acc[7]);
            up[2] = make_float4(acc[8], acc[9], acc[10], acc[11]);
            up[3] = make_float4(acc[12], acc[13], acc[14], acc[15]);
            up[4] = make_float4(acc[16], acc[17], acc[18], acc[19]);
            up[5] = make_float4(acc[20], 0.f, 0.f, 0.f);
        }
        float mx = acc[0];
        #pragma unroll
        for (int o = 1; o < NC; o++) mx = fmaxf(mx, acc[o]);
        float sum = 0.f;
        #pragma unroll
        for (int o = 0; o < NC; o++) { acc[o] = __expf(acc[o] - mx); sum += acc[o]; }
        const float inv = 1.f / sum;
        #pragma unroll
        for (int o = 0; o < NC; o++) acc[o] *= inv;
        {
            float4* sp = (float4*)(s_pm + (size_t)px * CP);
            sp[0] = make_float4(acc[0], acc[1], acc[2], acc[3]);
            sp[1] = make_float4(acc[4], acc[5], acc[6], acc[7]);
            sp[2] = make_float4(acc[8], acc[9], acc[10], acc[11]);
            sp[3] = make_float4(acc[12], acc[13], acc[14], acc[15]);
            sp[4] = make_float4(acc[16], acc[17], acc[18], acc[19]);
            sp[5] = make_float4(acc[20], 1.f, 0.f, 0.f);
        }
        #pragma unroll
        for (int o = 0; o < NC; o++) s_cm[(size_t)o * NPIX + px] = acc[o];
        s_cm[(size_t)21 * NPIX + px] = 1.f;

        const float fv[5] = {(float)j * (1.0f / 160.0f), (float)i * (1.0f / 160.0f),
                             img[0 * NPIX + px] * (1.0f / 3.0f),
                             img[1 * NPIX + px] * (1.0f / 3.0f),
                             img[2 * NPIX + px] * (1.0f / 3.0f)};
        const float env = __expf(-0.5f * (fv[0]*fv[0] + fv[1]*fv[1] + fv[2]*fv[2] +
                                          fv[3]*fv[3] + fv[4]*fv[4]));
        #pragma unroll
        for (int v = 0; v < 5; v++) {
            float p = 1.f;
            #pragma unroll
            for (int e = 0; e < 5; e++) { pt[tid * 25 + v * 5 + e] = p; p *= fv[v]; }
        }
        for (int m = 0; m < NMON; m++) {
            float p = env * sg_sh[m];
            p *= pt[tid * 25 + 0 + (int)ex_sh[m * 5 + 0]];
            p *= pt[tid * 25 + 5 + (int)ex_sh[m * 5 + 1]];
            p *= pt[tid * 25 + 10 + (int)ex_sh[m * 5 + 2]];
            p *= pt[tid * 25 + 15 + (int)ex_sh[m * 5 + 3]];
            p *= pt[tid * 25 + 20 + (int)ex_sh[m * 5 + 4]];
            phi[(size_t)m * NPIX + px] = p;
        }
    }
    gbar(bar, 0);

    // ================= iterations =================
    for (int it = 0; it < NITER; it++) {
        float* Mc = M + (it & 1) * MPAD;
        float* Mn = M + ((it + 1) & 1) * MPAD;

        // ---- phase A: stage1 tiles (432 block-tasks) + conv-x (792) ----
        for (int bt = bid; bt < NMG * 36 + NCH * 36; bt += NBLK) {
            if (bt < NMG * 36) {
                const int g = bt / 36, chunk = bt % 36;
                const int m0 = g * MG;
                const int mcnt = (NMON - m0 < MG) ? (NMON - m0) : MG;
                float* s_sh = smem;
                float* p_sh = smem + NCH * LDSS;
                __syncthreads();
                {
                    const float4* sp =
                        (const float4*)(s_pm + (size_t)(chunk * 256 + tid) * CP);
                    #pragma unroll
                    for (int v = 0; v < 6; v++) {
                        const float4 t = sp[v];
                        const int c = 4 * v;
                        if (c < NCH)     s_sh[c * LDSS + tid] = t.x;
                        if (c + 1 < NCH) s_sh[(c + 1) * LDSS + tid] = t.y;
                        if (c + 2 < NCH) s_sh[(c + 2) * LDSS + tid] = t.z;
                        if (c + 3 < NCH) s_sh[(c + 3) * LDSS + tid] = t.w;
                    }
                }
                for (int idx = tid; idx < mcnt * 64; idx += 256) {
                    const int mm = idx >> 6, p4 = idx & 63;
                    const float4 t = *(const float4*)(phi + (size_t)(m0 + mm) * NPIX +
                                                      chunk * 256 + p4 * 4);
                    *(float4*)(p_sh + mm * LDSS + p4 * 4) = t;
                }
                __syncthreads();
                const int c = tid % NCH, msub = tid / NCH;
                if (msub < mcnt) {
                    const float* sr = s_sh + c * LDSS;
                    const float* pr = p_sh + msub * LDSS;
                    float acc = 0.f;
                    for (int p4 = 0; p4 < 64; p4++) {
                        const float4 sv = *(const float4*)(sr + p4 * 4);
                        const float4 pv = *(const float4*)(pr + p4 * 4);
                        acc += pv.x * sv.x + pv.y * sv.y + pv.z * sv.z + pv.w * sv.w;
                    }
                    atomicAdd(&Mc[(m0 + msub) * NCH + c], acc);
                }
            } else {
                const int u2 = bt - NMG * 36;
                const int ch = u2 / 36, pc = u2 % 36;
                const int n = pc * 256 + tid, j = n % IMW;
                const float* row = s_cm + (size_t)ch * NPIX + (n - j);
                float a = GW[0] * row[j];
                #pragma unroll
                for (int d = 1; d <= RAD; d++) {
                    const float l = (j - d >= 0) ? row[j - d] : 0.f;
                    const float r = (j + d < IMW) ? row[j + d] : 0.f;
                    a = fmaf(GW[d], l + r, a);
                }
                sx[(size_t)ch * NPIX + n] = a;
            }
        }
        gbar(bar, 1 + 2 * it);

        // ---- phase B: conv-y + stage2 + combine + softmax (288 tasks) ----
        {
            float* Msh = smem;             // 3024
            float* phi_sh = smem + 3024;   // 4032
            float* cy_sh = smem + 7056;    // 800
            float* blv_sh = smem + 7856;   // 800
            float* mp_sh = smem + 8656;    // 768
            float* q_sh = smem + 9424;     // 768
            float* wsh = smem + 10192;     // 1449
            const int px0 = bid * 32;
            const int i0 = px0 / IMW;

            __syncthreads();
            for (int idx = tid; idx < NMON * CP; idx += 256) {
                const int mm = idx / CP, c = idx % CP;
                Msh[idx] = (c < NCH) ? Mc[mm * NCH + c] : 0.f;
            }
            for (int idx = tid; idx < 441; idx += 256) {
                wsh[idx] = sp_w[idx]; wsh[441 + idx] = bl_w[idx];
                wsh[882 + idx] = comp_w[idx];
            }
            if (tid < 21) {
                wsh[1323 + tid] = sp_b[tid]; wsh[1344 + tid] = bl_b[tid];
                wsh[1365 + tid] = comp_b[tid];
            }
            if (bid < 11) {
                const int idx = bid * 256 + tid;
                if (idx < 2772) Mn[idx] = 0.f;
            }
            for (int idx = tid; idx < NMON * 8; idx += 256) {
                const int m = idx >> 3, g = idx & 7;
                *(float4*)(phi_sh + m * 32 + g * 4) =
                    *(const float4*)(phi + (size_t)m * NPIX + px0 + g * 4);
            }
            for (int task = tid; task < 24 * 32; task += 256) {
                const int ch = task >> 5, p = task & 31;
                if (ch < NCH) {
                    const int n = px0 + p;
                    const float* plane = sx + (size_t)ch * NPIX;
                    float a = GW[0] * plane[n];
                    #pragma unroll
                    for (int d = 1; d <= RAD; d++) {
                        const float t = (i0 - d >= 0) ? plane[n - d * IMW] : 0.f;
                        const float b = (i0 + d < IMH) ? plane[n + d * IMW] : 0.f;
                        a = fmaf(GW[d], t + b, a);
                    }
                    cy_sh[p * 25 + ch] = a;
                }
            }
            __syncthreads();
            {
                const int p = tid & 31, c0 = (tid >> 5) * 3;
                float a0 = 0.f, a1 = 0.f, a2 = 0.f;
                for (int mm = 0; mm < NMON; mm++) {
                    const float ph = phi_sh[mm * 32 + p];
                    const float* Mr = Msh + mm * CP + c0;
                    a0 = fmaf(ph, Mr[0], a0);
                    a1 = fmaf(ph, Mr[1], a1);
                    a2 = fmaf(ph, Mr[2], a2);
                }
                if (c0 < NCH)     blv_sh[p * 25 + c0] = a0;
                if (c0 + 1 < NCH) blv_sh[p * 25 + c0 + 1] = a1;
                if (c0 + 2 < NCH) blv_sh[p * 25 + c0 + 2] = a2;
            }
            __syncthreads();
            for (int t = tid; t < 672; t += 256) {
                const int p = t & 31, o = t >> 5;
                const float* cyr = cy_sh + p * 25;
                const float* blr = blv_sh + p * 25;
                float dS = 0.f, dB = 0.f;
                #pragma unroll
                for (int c = 0; c < NC; c++) {
                    dS = fmaf(wsh[o * NC + c], cyr[c], dS);
                    dB = fmaf(wsh[441 + o * NC + c], blr[c], dB);
                }
                mp_sh[p * CP + o] = wsh[1323 + o] + wsh[1344 + o] +
                                    dS / cyr[21] + dB / blr[21];
            }
            __syncthreads();
            for (int t = tid; t < 672; t += 256) {
                const int p = t & 31, o = t >> 5;
                const float* mpr = mp_sh + p * CP;
                float d = wsh[1365 + o];
                #pragma unroll
                for (int c = 0; c < NC; c++)
                    d = fmaf(wsh[882 + o * NC + c], mpr[c], d);
                q_sh[p * CP + o] = u_pm[(size_t)(px0 + p) * CP + o] - d;
            }
            __syncthreads();
            if (tid < 32) {
                const int n = px0 + tid;
                float q[NC];
                #pragma unroll
                for (int o = 0; o < NC; o++) q[o] = q_sh[tid * CP + o];
                float mx = q[0];
                #pragma unroll
                for (int o = 1; o < NC; o++) mx = fmaxf(mx, q[o]);
                float sum = 0.f;
                #pragma unroll
                for (int o = 0; o < NC; o++) { q[o] = __expf(q[o] - mx); sum += q[o]; }
                const float inv = 1.f / sum;
                #pragma unroll
                for (int o = 0; o < NC; o++) q[o] *= inv;

                float4* sp = (float4*)(s_pm + (size_t)n * CP);
                sp[0] = make_float4(q[0], q[1], q[2], q[3]);
                sp[1] = make_float4(q[4], q[5], q[6], q[7]);
                sp[2] = make_float4(q[8], q[9], q[10], q[11]);
                sp[3] = make_float4(q[12], q[13], q[14], q[15]);
                sp[4] = make_float4(q[16], q[17], q[18], q[19]);
                sp[5] = make_float4(q[20], 1.f, 0.f, 0.f);
                #pragma unroll
                for (int o = 0; o < NC; o++) s_cm[(size_t)o * NPIX + n] = q[o];
                s_cm[(size_t)21 * NPIX + n] = 1.f;
                if (it == NITER - 1)
                    #pragma unroll
                    for (int o = 0; o < NC; o++) out[(size_t)o * NPIX + n] = q[o];
            }
        }
        if (it < NITER - 1) gbar(bar, 2 + 2 * it);
    }
}

extern "C" void kernel_launch(void* const* d_in, const int* in_sizes, int n_in,
                              void* d_out, int out_size, void* d_ws, size_t ws_size,
                              hipStream_t stream) {
    const float* img    = (const float*)d_in[0];
    const float* net_w  = (const float*)d_in[1];
    const float* net_b  = (const float*)d_in[2];
    const float* sp_w   = (const float*)d_in[3];
    const float* sp_b   = (const float*)d_in[4];
    const float* bl_w   = (const float*)d_in[5];
    const float* bl_b   = (const float*)d_in[6];
    const float* comp_w = (const float*)d_in[7];
    const float* comp_b = (const float*)d_in[8];

    unsigned* bar = (unsigned*)d_ws;             // 16 slots
    float* M    = (float*)d_ws + 16;             // [2][MPAD]
    float* u_pm = M + 2 * MPAD;                  // [NPIX][24]
    float* s_pm = u_pm + (size_t)NPIX * CP;      // [NPIX][24]
    float* s_cm = s_pm + (size_t)NPIX * CP;      // [22][NPIX]
    float* sx   = s_cm + (size_t)NCH * NPIX;     // [22][NPIX]
    float* phi  = sx + (size_t)NCH * NPIX;       // [126][NPIX]

    hipMemsetAsync(d_ws, 0, (16 + 2 * MPAD) * sizeof(float), stream);
    mega_kernel<<<dim3(NBLK), dim3(256), 0, stream>>>(
        img, net_w, net_b, sp_w, sp_b, bl_w, bl_b, comp_w, comp_b,
        bar, M, u_pm, s_pm, s_cm, sx, phi, (float*)d_out);
}

// Round 12
// 375.813 us; speedup vs baseline: 4.5358x; 2.2144x over previous
//
#include <hip/hip_runtime.h>

#define NPIX 9216
#define IMH 96
#define IMW 96
#define NC 21
#define NCH 22          // 21 classes + norm channel
#define NMON 126        // monomials of degree <=4 in 5 vars
#define RAD 15
#define NITER 5
#define MSZ 2772        // 126*22, one M buffer
#define SP 97           // s_sh pitch (97%32=1: bank-safe)
#define QP 25           // pixel-major pitch (25 coprime 32)

// spatial taps exp(-d^2/18), sigma=3
__constant__ float GW[16] = {
    1.0f, 0.945959f, 0.800737f, 0.606531f, 0.411112f, 0.249352f,
    0.135335f, 0.0657285f, 0.0285655f, 0.0111090f, 0.00386592f,
    0.00120386f, 0.000335463f, 8.36523e-05f, 1.86640e-05f, 3.72665e-06f};

// near-minimax deg-4 poly for exp(t) on [0, 1.0384] (all coeffs > 0)
__constant__ float d_bk[5] = {1.000000f, 0.998959f, 0.509936f, 0.139441f, 0.070024f};

// ---- shared A-part: stage1 (phi^T s -> M, atomic) + conv-x (s -> sx) ----
// s_sh: [22][SP] fresh softmax output for this row. phi_g: global phi base.
__device__ __forceinline__ void a_part(
    const float* s_sh, const float* __restrict__ phi, int base,
    float* __restrict__ Mdst, float* __restrict__ sx_out, int tid)
{
    for (int t = tid; t < MSZ; t += 256) {
        const int m = t / NCH, c = t % NCH;
        const float* pr = phi + (size_t)m * NPIX + base;
        const float* sr = s_sh + c * SP;
        float acc = 0.f;
        #pragma unroll 8
        for (int px = 0; px < 96; px++) acc = fmaf(pr[px], sr[px], acc);
        atomicAdd(&Mdst[t], acc);
    }
    for (int t = tid; t < NCH * 96; t += 256) {
        const int px = t % 96, ch = t / 96;
        const float* sr = s_sh + ch * SP;
        float a = GW[0] * sr[px];
        #pragma unroll
        for (int d = 1; d <= RAD; d++) {
            const float l = (px - d >= 0) ? sr[px - d] : 0.f;
            const float r = (px + d < 96) ? sr[px + d] : 0.f;
            a = fmaf(GW[d], l + r, a);
        }
        sx_out[(size_t)ch * NPIX + base + px] = a;
    }
}

// ---- P: conv + softmax + features + phi + stage1 + conv-x (1 row/block) ----
__global__ __launch_bounds__(256) void prep_kernel(
    const float* __restrict__ img, const float* __restrict__ net_w,
    const float* __restrict__ net_b,
    float* __restrict__ u, float* __restrict__ phi,
    float* __restrict__ M0, float* __restrict__ sx_out)
{
    __shared__ float wsh[588];          // conv w + b
    __shared__ float sg_sh[NMON];
    __shared__ float ex_sh[NMON * 5];
    __shared__ float pt[96 * QP];       // pow tables per px
    __shared__ float env[96];
    __shared__ float cq[96 * QP];       // conv result staging
    __shared__ float s_sh[NCH * SP];
    const int tid = threadIdx.x, row = blockIdx.x, base = row * 96;

    for (int i = tid; i < 567; i += 256) wsh[i] = net_w[i];
    if (tid < 21) wsh[567 + tid] = net_b[tid];
    for (int m = tid; m < NMON; m += 256) {
        int e1 = 0, e2 = 0, e3 = 0, e4 = 0, e5 = 0, cnt = 0;
        bool done = false;
        for (int a = 0; a <= 4 && !done; a++)
            for (int b2 = 0; b2 <= 4 - a && !done; b2++)
                for (int c = 0; c <= 4 - a - b2 && !done; c++)
                    for (int d = 0; d <= 4 - a - b2 - c && !done; d++) {
                        const int rem = 4 - a - b2 - c - d;
                        if (m - cnt <= rem) {
                            e1 = a; e2 = b2; e3 = c; e4 = d; e5 = m - cnt;
                            done = true;
                        } else cnt += rem + 1;
                    }
        const float fact[5] = {1.f, 1.f, 2.f, 6.f, 24.f};
        const int k = e1 + e2 + e3 + e4 + e5;
        sg_sh[m] = sqrtf(d_bk[k] * fact[k] /
                         (fact[e1] * fact[e2] * fact[e3] * fact[e4] * fact[e5]));
        ex_sh[m * 5 + 0] = (float)e1; ex_sh[m * 5 + 1] = (float)e2;
        ex_sh[m * 5 + 2] = (float)e3; ex_sh[m * 5 + 3] = (float)e4;
        ex_sh[m * 5 + 4] = (float)e5;
    }
    __syncthreads();

    // unary conv: task = (px, class)
    for (int t = tid; t < 96 * NC; t += 256) {
        const int px = t % 96, o = t / 96;
        float acc = wsh[567 + o];
        for (int ci = 0; ci < 3; ci++)
            for (int ky = 0; ky < 3; ky++)
                for (int kx = 0; kx < 3; kx++) {
                    const int ii = row + ky - 1, jj = px + kx - 1;
                    float v = 0.f;
                    if (ii >= 0 && ii < IMH && jj >= 0 && jj < IMW)
                        v = img[ci * NPIX + ii * IMW + jj];
                    acc = fmaf(v, wsh[o * 27 + (ci * 3 + ky) * 3 + kx], acc);
                }
        cq[px * QP + o] = acc;
        u[(size_t)o * NPIX + base + px] = acc;
    }
    // features + pow tables (one thread per px)
    if (tid < 96) {
        const float fv[5] = {(float)tid * (1.0f / 160.0f),
                             (float)row * (1.0f / 160.0f),
                             img[0 * NPIX + base + tid] * (1.0f / 3.0f),
                             img[1 * NPIX + base + tid] * (1.0f / 3.0f),
                             img[2 * NPIX + base + tid] * (1.0f / 3.0f)};
        env[tid] = __expf(-0.5f * (fv[0]*fv[0] + fv[1]*fv[1] + fv[2]*fv[2] +
                                   fv[3]*fv[3] + fv[4]*fv[4]));
        #pragma unroll
        for (int v = 0; v < 5; v++) {
            float p = 1.f;
            #pragma unroll
            for (int e = 0; e < 5; e++) { pt[tid * QP + v * 5 + e] = p; p *= fv[v]; }
        }
    }
    __syncthreads();
    // softmax (one thread per px)
    if (tid < 96) {
        float a[NC];
        #pragma unroll
        for (int o = 0; o < NC; o++) a[o] = cq[tid * QP + o];
        float mx = a[0];
        #pragma unroll
        for (int o = 1; o < NC; o++) mx = fmaxf(mx, a[o]);
        float sum = 0.f;
        #pragma unroll
        for (int o = 0; o < NC; o++) { a[o] = __expf(a[o] - mx); sum += a[o]; }
        const float inv = 1.f / sum;
        #pragma unroll
        for (int o = 0; o < NC; o++) s_sh[o * SP + tid] = a[o] * inv;
        s_sh[21 * SP + tid] = 1.f;
    }
    // phi rows
    for (int t = tid; t < NMON * 96; t += 256) {
        const int px = t % 96, m = t / 96;
        float p = env[px] * sg_sh[m];
        p *= pt[px * QP + 0 + (int)ex_sh[m * 5 + 0]];
        p *= pt[px * QP + 5 + (int)ex_sh[m * 5 + 1]];
        p *= pt[px * QP + 10 + (int)ex_sh[m * 5 + 2]];
        p *= pt[px * QP + 15 + (int)ex_sh[m * 5 + 3]];
        p *= pt[px * QP + 20 + (int)ex_sh[m * 5 + 4]];
        phi[(size_t)m * NPIX + base + px] = p;
    }
    __syncthreads();   // drains phi global writes; s_sh complete

    a_part(s_sh, phi, base, M0, sx_out, tid);
}

// ---- KBA: conv-y + stage2 + combine + softmax (+ stage1/conv-x of next it) ----
__global__ __launch_bounds__(256) void kba_kernel(
    const float* __restrict__ sx_in, float* __restrict__ sx_out,
    const float* __restrict__ phi,
    const float* __restrict__ Mcur, float* __restrict__ Mnext,
    float* __restrict__ Mzero, const float* __restrict__ u,
    const float* __restrict__ sp_w, const float* __restrict__ sp_b,
    const float* __restrict__ bl_w, const float* __restrict__ bl_b,
    const float* __restrict__ comp_w, const float* __restrict__ comp_b,
    float* __restrict__ out, int write_out, int doA)
{
    __shared__ float Msh[NMON * 24];    // pitch 24, cols 22/23 = 0
    __shared__ float cy_sh[96 * QP];    // conv-y; later aliased as q
    __shared__ float blv_sh[96 * QP];
    __shared__ float mp_sh[96 * QP];
    __shared__ float s_sh[NCH * SP];
    __shared__ float wsh[1449];
    const int tid = threadIdx.x, row = blockIdx.x, base = row * 96;

    for (int t = tid; t < NMON * 24; t += 256) {
        const int m = t / 24, c = t % 24;
        Msh[t] = (c < NCH) ? Mcur[m * NCH + c] : 0.f;
    }
    for (int i = tid; i < 441; i += 256) {
        wsh[i] = sp_w[i]; wsh[441 + i] = bl_w[i]; wsh[882 + i] = comp_w[i];
    }
    if (tid < 21) {
        wsh[1323 + tid] = sp_b[tid]; wsh[1344 + tid] = bl_b[tid];
        wsh[1365 + tid] = comp_b[tid];
    }
    {   // zero the M buffer consumed last dispatch (safe: nobody touches it now)
        const int idx = row * 29 + tid;
        if (tid < 29 && idx < MSZ) Mzero[idx] = 0.f;
    }
    // conv-y (global sx_in, rows row±15)
    for (int t = tid; t < NCH * 96; t += 256) {
        const int px = t % 96, ch = t / 96;
        const float* plane = sx_in + (size_t)ch * NPIX;
        float a = GW[0] * plane[base + px];
        #pragma unroll
        for (int d = 1; d <= RAD; d++) {
            const float tp = (row - d >= 0) ? plane[base - d * IMW + px] : 0.f;
            const float bt = (row + d < IMH) ? plane[base + d * IMW + px] : 0.f;
            a = fmaf(GW[d], tp + bt, a);
        }
        cy_sh[px * QP + ch] = a;
    }
    __syncthreads();

    // stage2: task = (px, 3-channel group); phi read from global (L1/L2-hot)
    for (int t = tid; t < 96 * 8; t += 256) {
        const int px = t % 96, c0 = (t / 96) * 3;
        float a0 = 0.f, a1 = 0.f, a2 = 0.f;
        for (int m = 0; m < NMON; m++) {
            const float ph = phi[(size_t)m * NPIX + base + px];
            const float* Mr = Msh + m * 24 + c0;
            a0 = fmaf(ph, Mr[0], a0);
            a1 = fmaf(ph, Mr[1], a1);
            a2 = fmaf(ph, Mr[2], a2);
        }
        blv_sh[px * QP + c0] = a0;
        if (c0 + 1 < NCH) blv_sh[px * QP + c0 + 1] = a1;
        if (c0 + 2 < NCH) blv_sh[px * QP + c0 + 2] = a2;
    }
    __syncthreads();

    // mp = sp_b + bl_b + (sp_w@cy)/cy_norm + (bl_w@blv)/blv_norm
    for (int t = tid; t < 96 * NC; t += 256) {
        const int px = t % 96, o = t / 96;
        const float* cyr = cy_sh + px * QP;
        const float* blr = blv_sh + px * QP;
        float dS = 0.f, dB = 0.f;
        #pragma unroll
        for (int c = 0; c < NC; c++) {
            dS = fmaf(wsh[o * NC + c], cyr[c], dS);
            dB = fmaf(wsh[441 + o * NC + c], blr[c], dB);
        }
        mp_sh[px * QP + o] = wsh[1323 + o] + wsh[1344 + o] +
                             dS / cyr[21] + dB / blr[21];
    }
    __syncthreads();

    // q = u - (comp_w @ mp + comp_b)   (q aliases cy_sh)
    for (int t = tid; t < 96 * NC; t += 256) {
        const int px = t % 96, o = t / 96;
        const float* mpr = mp_sh + px * QP;
        float d = wsh[1365 + o];
        #pragma unroll
        for (int c = 0; c < NC; c++) d = fmaf(wsh[882 + o * NC + c], mpr[c], d);
        cy_sh[px * QP + o] = u[(size_t)o * NPIX + base + px] - d;
    }
    __syncthreads();

    // softmax per px -> s_sh (and out on last iteration)
    if (tid < 96) {
        float q[NC];
        #pragma unroll
        for (int o = 0; o < NC; o++) q[o] = cy_sh[tid * QP + o];
        float mx = q[0];
        #pragma unroll
        for (int o = 1; o < NC; o++) mx = fmaxf(mx, q[o]);
        float sum = 0.f;
        #pragma unroll
        for (int o = 0; o < NC; o++) { q[o] = __expf(q[o] - mx); sum += q[o]; }
        const float inv = 1.f / sum;
        #pragma unroll
        for (int o = 0; o < NC; o++) {
            const float sv = q[o] * inv;
            s_sh[o * SP + tid] = sv;
            if (write_out) out[(size_t)o * NPIX + base + tid] = sv;
        }
        s_sh[21 * SP + tid] = 1.f;
    }
    __syncthreads();

    if (doA) a_part(s_sh, phi, base, Mnext, sx_out, tid);
}

extern "C" void kernel_launch(void* const* d_in, const int* in_sizes, int n_in,
                              void* d_out, int out_size, void* d_ws, size_t ws_size,
                              hipStream_t stream) {
    const float* img    = (const float*)d_in[0];
    const float* net_w  = (const float*)d_in[1];
    const float* net_b  = (const float*)d_in[2];
    const float* sp_w   = (const float*)d_in[3];
    const float* sp_b   = (const float*)d_in[4];
    const float* bl_w   = (const float*)d_in[5];
    const float* bl_b   = (const float*)d_in[6];
    const float* comp_w = (const float*)d_in[7];
    const float* comp_b = (const float*)d_in[8];

    float* M   = (float*)d_ws;                   // [3][2772]
    float* u   = M + 3 * MSZ;                    // [21][NPIX]
    float* sx  = u + (size_t)NC * NPIX;          // [2][22][NPIX]
    float* phi = sx + (size_t)2 * NCH * NPIX;    // [126][NPIX]

    float* out = (float*)d_out;

    hipMemsetAsync(M, 0, 3 * MSZ * sizeof(float), stream);
    prep_kernel<<<dim3(96), dim3(256), 0, stream>>>(
        img, net_w, net_b, u, phi, M, sx);
    for (int it = 0; it < NITER; it++) {
        float* Mcur  = M + (it % 3) * MSZ;
        float* Mnext = M + ((it + 1) % 3) * MSZ;
        float* Mzero = M + ((it + 2) % 3) * MSZ;
        kba_kernel<<<dim3(96), dim3(256), 0, stream>>>(
            sx + (size_t)(it & 1) * NCH * NPIX,
            sx + (size_t)((it + 1) & 1) * NCH * NPIX,
            phi, Mcur, Mnext, Mzero, u,
            sp_w, sp_b, bl_w, bl_b, comp_w, comp_b,
            out, it == NITER - 1 ? 1 : 0, it < NITER - 1 ? 1 : 0);
    }
}

// Round 13
// 238.183 us; speedup vs baseline: 7.1567x; 1.5778x over previous
//
#include <hip/hip_runtime.h>

#define NPIX 9216
#define IMH 96
#define IMW 96
#define NC 21
#define NCH 22          // 21 classes + norm channel
#define NMON 126        // monomials of degree <=4 in 5 vars
#define RAD 15
#define NITER 5
#define MSZ 2772        // 126*22, one M buffer
#define SP 97           // s_sh pitch (97%32=1: bank-safe)
#define QP 25           // pixel-major pitch (25 coprime 32)
#define NT 1024         // threads per block: 16 waves -> 6 waves/CU at grid 96

// spatial taps exp(-d^2/18), sigma=3
__constant__ float GW[16] = {
    1.0f, 0.945959f, 0.800737f, 0.606531f, 0.411112f, 0.249352f,
    0.135335f, 0.0657285f, 0.0285655f, 0.0111090f, 0.00386592f,
    0.00120386f, 0.000335463f, 8.36523e-05f, 1.86640e-05f, 3.72665e-06f};

// near-minimax deg-4 poly for exp(t) on [0, 1.0384] (all coeffs > 0)
__constant__ float d_bk[5] = {1.000000f, 0.998959f, 0.509936f, 0.139441f, 0.070024f};

// ---- shared A-part: stage1 (phi^T s -> M, atomic) + conv-x (s -> sx) ----
__device__ __forceinline__ void a_part(
    const float* s_sh, const float* __restrict__ phi, int base,
    float* __restrict__ Mdst, float* __restrict__ sx_out, int tid)
{
    for (int t = tid; t < MSZ; t += NT) {
        const int m = t / NCH, c = t % NCH;
        const float* pr = phi + (size_t)m * NPIX + base;
        const float* sr = s_sh + c * SP;
        float acc = 0.f;
        #pragma unroll
        for (int p4 = 0; p4 < 24; p4++) {
            const float4 pv = *(const float4*)(pr + p4 * 4);
            acc += pv.x * sr[p4 * 4] + pv.y * sr[p4 * 4 + 1] +
                   pv.z * sr[p4 * 4 + 2] + pv.w * sr[p4 * 4 + 3];
        }
        atomicAdd(&Mdst[t], acc);
    }
    for (int t = tid; t < NCH * 96; t += NT) {
        const int px = t % 96, ch = t / 96;
        const float* sr = s_sh + ch * SP;
        float a = GW[0] * sr[px];
        #pragma unroll
        for (int d = 1; d <= RAD; d++) {
            const float l = (px - d >= 0) ? sr[px - d] : 0.f;
            const float r = (px + d < 96) ? sr[px + d] : 0.f;
            a = fmaf(GW[d], l + r, a);
        }
        sx_out[(size_t)ch * NPIX + base + px] = a;
    }
}

// ---- P: conv + softmax + features + phi + stage1 + conv-x (1 row/block) ----
__global__ __launch_bounds__(NT) void prep_kernel(
    const float* __restrict__ img, const float* __restrict__ net_w,
    const float* __restrict__ net_b,
    float* __restrict__ u, float* __restrict__ phi,
    float* __restrict__ M0, float* __restrict__ sx_out)
{
    __shared__ float wsh[588];          // conv w + b
    __shared__ float sg_sh[NMON];
    __shared__ float ex_sh[NMON * 5];
    __shared__ float pt[96 * QP];       // pow tables per px
    __shared__ float env[96];
    __shared__ float cq[96 * QP];       // conv result staging
    __shared__ float s_sh[NCH * SP];
    const int tid = threadIdx.x, row = blockIdx.x, base = row * 96;

    for (int i = tid; i < 567; i += NT) wsh[i] = net_w[i];
    if (tid < 21) wsh[567 + tid] = net_b[tid];
    if (tid < NMON) {
        const int m = tid;
        int e1 = 0, e2 = 0, e3 = 0, e4 = 0, e5 = 0, cnt = 0;
        bool done = false;
        for (int a = 0; a <= 4 && !done; a++)
            for (int b2 = 0; b2 <= 4 - a && !done; b2++)
                for (int c = 0; c <= 4 - a - b2 && !done; c++)
                    for (int d = 0; d <= 4 - a - b2 - c && !done; d++) {
                        const int rem = 4 - a - b2 - c - d;
                        if (m - cnt <= rem) {
                            e1 = a; e2 = b2; e3 = c; e4 = d; e5 = m - cnt;
                            done = true;
                        } else cnt += rem + 1;
                    }
        const float fact[5] = {1.f, 1.f, 2.f, 6.f, 24.f};
        const int k = e1 + e2 + e3 + e4 + e5;
        sg_sh[m] = sqrtf(d_bk[k] * fact[k] /
                         (fact[e1] * fact[e2] * fact[e3] * fact[e4] * fact[e5]));
        ex_sh[m * 5 + 0] = (float)e1; ex_sh[m * 5 + 1] = (float)e2;
        ex_sh[m * 5 + 2] = (float)e3; ex_sh[m * 5 + 3] = (float)e4;
        ex_sh[m * 5 + 4] = (float)e5;
    }
    __syncthreads();

    // unary conv: task = (px, class)
    for (int t = tid; t < 96 * NC; t += NT) {
        const int px = t % 96, o = t / 96;
        float acc = wsh[567 + o];
        for (int ci = 0; ci < 3; ci++)
            for (int ky = 0; ky < 3; ky++)
                for (int kx = 0; kx < 3; kx++) {
                    const int ii = row + ky - 1, jj = px + kx - 1;
                    float v = 0.f;
                    if (ii >= 0 && ii < IMH && jj >= 0 && jj < IMW)
                        v = img[ci * NPIX + ii * IMW + jj];
                    acc = fmaf(v, wsh[o * 27 + (ci * 3 + ky) * 3 + kx], acc);
                }
        cq[px * QP + o] = acc;
        u[(size_t)o * NPIX + base + px] = acc;
    }
    // features + pow tables (one thread per px)
    if (tid < 96) {
        const float fv[5] = {(float)tid * (1.0f / 160.0f),
                             (float)row * (1.0f / 160.0f),
                             img[0 * NPIX + base + tid] * (1.0f / 3.0f),
                             img[1 * NPIX + base + tid] * (1.0f / 3.0f),
                             img[2 * NPIX + base + tid] * (1.0f / 3.0f)};
        env[tid] = __expf(-0.5f * (fv[0]*fv[0] + fv[1]*fv[1] + fv[2]*fv[2] +
                                   fv[3]*fv[3] + fv[4]*fv[4]));
        #pragma unroll
        for (int v = 0; v < 5; v++) {
            float p = 1.f;
            #pragma unroll
            for (int e = 0; e < 5; e++) { pt[tid * QP + v * 5 + e] = p; p *= fv[v]; }
        }
    }
    __syncthreads();
    // softmax (one thread per px)
    if (tid < 96) {
        float a[NC];
        #pragma unroll
        for (int o = 0; o < NC; o++) a[o] = cq[tid * QP + o];
        float mx = a[0];
        #pragma unroll
        for (int o = 1; o < NC; o++) mx = fmaxf(mx, a[o]);
        float sum = 0.f;
        #pragma unroll
        for (int o = 0; o < NC; o++) { a[o] = __expf(a[o] - mx); sum += a[o]; }
        const float inv = 1.f / sum;
        #pragma unroll
        for (int o = 0; o < NC; o++) s_sh[o * SP + tid] = a[o] * inv;
        s_sh[21 * SP + tid] = 1.f;
    }
    // phi rows
    for (int t = tid; t < NMON * 96; t += NT) {
        const int px = t % 96, m = t / 96;
        float p = env[px] * sg_sh[m];
        p *= pt[px * QP + 0 + (int)ex_sh[m * 5 + 0]];
        p *= pt[px * QP + 5 + (int)ex_sh[m * 5 + 1]];
        p *= pt[px * QP + 10 + (int)ex_sh[m * 5 + 2]];
        p *= pt[px * QP + 15 + (int)ex_sh[m * 5 + 3]];
        p *= pt[px * QP + 20 + (int)ex_sh[m * 5 + 4]];
        phi[(size_t)m * NPIX + base + px] = p;
    }
    __syncthreads();   // drains phi global writes; s_sh complete

    a_part(s_sh, phi, base, M0, sx_out, tid);
}

// ---- KBA: conv-y + stage2 + combine + softmax (+ stage1/conv-x of next it) ----
__global__ __launch_bounds__(NT) void kba_kernel(
    const float* __restrict__ sx_in, float* __restrict__ sx_out,
    const float* __restrict__ phi,
    const float* __restrict__ Mcur, float* __restrict__ Mnext,
    float* __restrict__ Mzero, const float* __restrict__ u,
    const float* __restrict__ sp_w, const float* __restrict__ sp_b,
    const float* __restrict__ bl_w, const float* __restrict__ bl_b,
    const float* __restrict__ comp_w, const float* __restrict__ comp_b,
    float* __restrict__ out, int write_out, int doA)
{
    __shared__ float Msh[NMON * 24];    // pitch 24, cols 22/23 = 0
    __shared__ float cy_sh[96 * QP];    // conv-y; later aliased as q
    __shared__ float blv_sh[96 * QP];
    __shared__ float mp_sh[96 * QP];
    __shared__ float s_sh[NCH * SP];
    __shared__ float wsh[1449];
    const int tid = threadIdx.x, row = blockIdx.x, base = row * 96;

    for (int t = tid; t < NMON * 24; t += NT) {
        const int m = t / 24, c = t % 24;
        Msh[t] = (c < NCH) ? Mcur[m * NCH + c] : 0.f;
    }
    for (int i = tid; i < 441; i += NT) {
        wsh[i] = sp_w[i]; wsh[441 + i] = bl_w[i]; wsh[882 + i] = comp_w[i];
    }
    if (tid < 21) {
        wsh[1323 + tid] = sp_b[tid]; wsh[1344 + tid] = bl_b[tid];
        wsh[1365 + tid] = comp_b[tid];
    }
    {   // zero the M buffer consumed last dispatch (safe: nobody touches it now)
        const int idx = row * 29 + tid;
        if (tid < 29 && idx < MSZ) Mzero[idx] = 0.f;
    }
    // conv-y (global sx_in, rows row±15)
    for (int t = tid; t < NCH * 96; t += NT) {
        const int px = t % 96, ch = t / 96;
        const float* plane = sx_in + (size_t)ch * NPIX;
        float a = GW[0] * plane[base + px];
        #pragma unroll
        for (int d = 1; d <= RAD; d++) {
            const float tp = (row - d >= 0) ? plane[base - d * IMW + px] : 0.f;
            const float bt = (row + d < IMH) ? plane[base + d * IMW + px] : 0.f;
            a = fmaf(GW[d], tp + bt, a);
        }
        cy_sh[px * QP + ch] = a;
    }
    __syncthreads();

    // stage2: task = (px, 3-channel group); phi read from global (coalesced)
    for (int t = tid; t < 96 * 8; t += NT) {
        const int px = t % 96, c0 = (t / 96) * 3;
        float a0 = 0.f, a1 = 0.f, a2 = 0.f;
        for (int m = 0; m < NMON; m++) {
            const float ph = phi[(size_t)m * NPIX + base + px];
            const float* Mr = Msh + m * 24 + c0;
            a0 = fmaf(ph, Mr[0], a0);
            a1 = fmaf(ph, Mr[1], a1);
            a2 = fmaf(ph, Mr[2], a2);
        }
        blv_sh[px * QP + c0] = a0;
        if (c0 + 1 < NCH) blv_sh[px * QP + c0 + 1] = a1;
        if (c0 + 2 < NCH) blv_sh[px * QP + c0 + 2] = a2;
    }
    __syncthreads();

    // mp = sp_b + bl_b + (sp_w@cy)/cy_norm + (bl_w@blv)/blv_norm
    for (int t = tid; t < 96 * NC; t += NT) {
        const int px = t % 96, o = t / 96;
        const float* cyr = cy_sh + px * QP;
        const float* blr = blv_sh + px * QP;
        float dS = 0.f, dB = 0.f;
        #pragma unroll
        for (int c = 0; c < NC; c++) {
            dS = fmaf(wsh[o * NC + c], cyr[c], dS);
            dB = fmaf(wsh[441 + o * NC + c], blr[c], dB);
        }
        mp_sh[px * QP + o] = wsh[1323 + o] + wsh[1344 + o] +
                             dS / cyr[21] + dB / blr[21];
    }
    __syncthreads();

    // q = u - (comp_w @ mp + comp_b)   (q aliases cy_sh; conv-y data dead)
    for (int t = tid; t < 96 * NC; t += NT) {
        const int px = t % 96, o = t / 96;
        const float* mpr = mp_sh + px * QP;
        float d = wsh[1365 + o];
        #pragma unroll
        for (int c = 0; c < NC; c++) d = fmaf(wsh[882 + o * NC + c], mpr[c], d);
        cy_sh[px * QP + o] = u[(size_t)o * NPIX + base + px] - d;
    }
    __syncthreads();

    // softmax per px -> s_sh (and out on last iteration)
    if (tid < 96) {
        float q[NC];
        #pragma unroll
        for (int o = 0; o < NC; o++) q[o] = cy_sh[tid * QP + o];
        float mx = q[0];
        #pragma unroll
        for (int o = 1; o < NC; o++) mx = fmaxf(mx, q[o]);
        float sum = 0.f;
        #pragma unroll
        for (int o = 0; o < NC; o++) { q[o] = __expf(q[o] - mx); sum += q[o]; }
        const float inv = 1.f / sum;
        #pragma unroll
        for (int o = 0; o < NC; o++) {
            const float sv = q[o] * inv;
            s_sh[o * SP + tid] = sv;
            if (write_out) out[(size_t)o * NPIX + base + tid] = sv;
        }
        s_sh[21 * SP + tid] = 1.f;
    }
    __syncthreads();

    if (doA) a_part(s_sh, phi, base, Mnext, sx_out, tid);
}

extern "C" void kernel_launch(void* const* d_in, const int* in_sizes, int n_in,
                              void* d_out, int out_size, void* d_ws, size_t ws_size,
                              hipStream_t stream) {
    const float* img    = (const float*)d_in[0];
    const float* net_w  = (const float*)d_in[1];
    const float* net_b  = (const float*)d_in[2];
    const float* sp_w   = (const float*)d_in[3];
    const float* sp_b   = (const float*)d_in[4];
    const float* bl_w   = (const float*)d_in[5];
    const float* bl_b   = (const float*)d_in[6];
    const float* comp_w = (const float*)d_in[7];
    const float* comp_b = (const float*)d_in[8];

    float* M   = (float*)d_ws;                   // [3][2772]
    float* u   = M + 3 * MSZ;                    // [21][NPIX]
    float* sx  = u + (size_t)NC * NPIX;          // [2][22][NPIX]
    float* phi = sx + (size_t)2 * NCH * NPIX;    // [126][NPIX]

    float* out = (float*)d_out;

    hipMemsetAsync(M, 0, 3 * MSZ * sizeof(float), stream);
    prep_kernel<<<dim3(96), dim3(NT), 0, stream>>>(
        img, net_w, net_b, u, phi, M, sx);
    for (int it = 0; it < NITER; it++) {
        float* Mcur  = M + (it % 3) * MSZ;
        float* Mnext = M + ((it + 1) % 3) * MSZ;
        float* Mzero = M + ((it + 2) % 3) * MSZ;
        kba_kernel<<<dim3(96), dim3(NT), 0, stream>>>(
            sx + (size_t)(it & 1) * NCH * NPIX,
            sx + (size_t)((it + 1) & 1) * NCH * NPIX,
            phi, Mcur, Mnext, Mzero, u,
            sp_w, sp_b, bl_w, bl_b, comp_w, comp_b,
            out, it == NITER - 1 ? 1 : 0, it < NITER - 1 ? 1 : 0);
    }
}